// Round 4
// baseline (285.601 us; speedup 1.0000x reference)
//
#include <hip/hip_runtime.h>

constexpr int N_VARS   = 2048;
constexpr int NODES    = 4096;
constexpr int N_LAYERS = 8;
constexpr int BATCH    = 8192;
constexpr int THREADS  = 256;
constexpr int RPB      = 2;                 // batch rows per block
constexpr int NPT      = NODES / THREADS;   // 16 nodes/thread/layer

// ---- bf16x2 word = row0 bf16 (low 16) | row1 bf16 (high 16) ----
__device__ __forceinline__ float bflo(unsigned w) { return __uint_as_float(w << 16); }
__device__ __forceinline__ float bfhi(unsigned w) { return __uint_as_float(w & 0xffff0000u); }
__device__ __forceinline__ unsigned bfpack(float a, float b) {   // RNE both
  unsigned ua = __float_as_uint(a), ub = __float_as_uint(b);
  ua = (ua + 0x7fffu + ((ua >> 16) & 1u)) >> 16;
  ub = (ub + 0x7fffu + ((ub >> 16) & 1u)) & 0xffff0000u;
  return ua | ub;
}

// MODE: 0 = pre-packed ushort4 (d_ws), 1 = raw int32, 2 = raw int64 words
template <int MODE>
__device__ __forceinline__ ushort4 get_idx(const void* p, int n) {
  if (MODE == 0) return ((const ushort4*)p)[n];
  if (MODE == 1) {
    int4 c = ((const int4*)p)[n];
    return make_ushort4((unsigned short)c.x, (unsigned short)c.y,
                        (unsigned short)c.z, (unsigned short)c.w);
  }
  const int* q = (const int*)p + (size_t)n * 8;
  return make_ushort4((unsigned short)q[0], (unsigned short)q[2],
                      (unsigned short)q[4], (unsigned short)q[6]);
}
template <int MODE> __device__ __forceinline__ size_t layer_bytes() {
  return MODE == 0 ? (size_t)NODES * 8 : MODE == 1 ? (size_t)NODES * 16
                                                   : (size_t)NODES * 32;
}

// Prod layer: gather fp32 float2 from A, multiply fp32, store bf16x2 to B.
template <int MODE>
__device__ __forceinline__ void prod_pass(const float2* A, unsigned* B,
                                          const void* idx, int t) {
#pragma unroll
  for (int i = 0; i < NPT; ++i) {
    const int n = t + i * THREADS;
    ushort4 c = get_idx<MODE>(idx, n);
    float2 a = A[c.x], b = A[c.y], d = A[c.z], e = A[c.w];
    B[n] = bfpack(a.x * b.x * d.x * e.x, a.y * b.y * d.y * e.y);
  }
}

// Sum layer: gather bf16x2 from B, add fp32, store fp32 float2 to A.
template <int MODE>
__device__ __forceinline__ void sum_pass(const unsigned* B, float2* A,
                                         const void* idx, int t) {
#pragma unroll
  for (int i = 0; i < NPT; ++i) {
    const int n = t + i * THREADS;
    ushort4 c = get_idx<MODE>(idx, n);
    unsigned a = B[c.x], b = B[c.y], d = B[c.z], e = B[c.w];
    A[n] = make_float2(bflo(a) + bflo(b) + bflo(d) + bflo(e),
                       bfhi(a) + bfhi(b) + bfhi(d) + bfhi(e));
  }
}

template <int MODE>
__device__ __forceinline__ void spn_body(const float* __restrict__ x,
                                         const unsigned char* __restrict__ marg,
                                         const void* __restrict__ idx,
                                         float* __restrict__ out,
                                         float2* A,          // 4096 fp32x2 = 32 KB
                                         unsigned* B) {      // 4096 bf16x2 = 16 KB
  const int t = threadIdx.x;
  const int row0 = blockIdx.x * RPB;
  const float* x0 = x + (size_t)row0 * N_VARS;
  const float* x1 = x0 + N_VARS;

#pragma unroll
  for (int i = 0; i < N_VARS / THREADS; ++i) {  // 8 iterations
    const int j = t + i * THREADS;
    const float a = x0[j], b = x1[j];
    const bool m = marg[j] != 0;
    A[j]          = make_float2(m ? 1.f : a,       m ? 1.f : b);
    A[N_VARS + j] = make_float2(m ? 1.f : 1.f - a, m ? 1.f : 1.f - b);
  }

  const char* ib = (const char*)idx;
  const size_t LB = layer_bytes<MODE>();
  __syncthreads();
  prod_pass<MODE>(A, B, ib + 0 * LB, t); __syncthreads();   // L0
  sum_pass <MODE>(B, A, ib + 1 * LB, t); __syncthreads();   // L1
  prod_pass<MODE>(A, B, ib + 2 * LB, t); __syncthreads();   // L2
  sum_pass <MODE>(B, A, ib + 3 * LB, t); __syncthreads();   // L3
  prod_pass<MODE>(A, B, ib + 4 * LB, t); __syncthreads();   // L4
  sum_pass <MODE>(B, A, ib + 5 * LB, t); __syncthreads();   // L5
  prod_pass<MODE>(A, B, ib + 6 * LB, t); __syncthreads();   // L6

  // L7 (sum) fused into node reduction.
  float s0 = 0.f, s1 = 0.f;
  {
    const void* L7 = ib + 7 * LB;
#pragma unroll
    for (int i = 0; i < NPT; ++i) {
      const int n = t + i * THREADS;
      ushort4 c = get_idx<MODE>(L7, n);
      unsigned a = B[c.x], b = B[c.y], d = B[c.z], e = B[c.w];
      s0 += bflo(a) + bflo(b) + bflo(d) + bflo(e);
      s1 += bfhi(a) + bfhi(b) + bfhi(d) + bfhi(e);
    }
  }
#pragma unroll
  for (int off = 32; off > 0; off >>= 1) {
    s0 += __shfl_down(s0, off);
    s1 += __shfl_down(s1, off);
  }
  if ((t & 63) == 0) A[t >> 6] = make_float2(s0, s1);
  __syncthreads();
  if (t == 0) {
    float2 tot = A[0];
#pragma unroll
    for (int w = 1; w < THREADS / 64; ++w) { tot.x += A[w].x; tot.y += A[w].y; }
    out[row0]     = tot.x;
    out[row0 + 1] = tot.y;
  }
}

__global__ __launch_bounds__(THREADS) void spn_packed(
    const float* __restrict__ x, const unsigned char* __restrict__ marg,
    const ushort4* __restrict__ idx, float* __restrict__ out) {
  __shared__ float2   A[NODES];   // 32 KB
  __shared__ unsigned B[NODES];   // 16 KB  -> 48 KB, 3 blocks/CU
  spn_body<0>(x, marg, idx, out, A, B);
}

__global__ __launch_bounds__(THREADS) void spn_raw(
    const float* __restrict__ x, const unsigned char* __restrict__ marg,
    const int* __restrict__ cidx, float* __restrict__ out) {
  __shared__ float2   A[NODES];
  __shared__ unsigned B[NODES];
  int acc = 0;  // int64 storage => odd words all zero (indices < 4096)
#pragma unroll
  for (int k = 0; k < 8; ++k) acc |= cidx[2 * k + 1];
  if (acc == 0) spn_body<2>(x, marg, cidx, out, A, B);
  else          spn_body<1>(x, marg, cidx, out, A, B);
}

// Pass 1: pack int64/int32 indices -> ushort4 per node.
__global__ void pack_idx(const int* __restrict__ cidx, ushort4* __restrict__ out) {
  const int g = blockIdx.x * blockDim.x + threadIdx.x;
  int acc = 0;
#pragma unroll
  for (int k = 0; k < 8; ++k) acc |= cidx[2 * k + 1];
  ushort4 r;
  if (acc == 0) {
    const int* p = cidx + (size_t)g * 8;
    r = make_ushort4((unsigned short)p[0], (unsigned short)p[2],
                     (unsigned short)p[4], (unsigned short)p[6]);
  } else {
    int4 c = ((const int4*)cidx)[g];
    r = make_ushort4((unsigned short)c.x, (unsigned short)c.y,
                     (unsigned short)c.z, (unsigned short)c.w);
  }
  out[g] = r;
}

// Pass 2: bank-conflict slot balancing. Prod/sum are commutative, so each
// node's 4 children can be permuted across the 4 gather instructions. One
// thread per (layer, wave, iter) instruction-group of 64 nodes; greedy:
// assign each child to the least-loaded (slot, bank) counter.
//   layer even -> reads A (float2, 8 B granule)  -> bank-pair = c & 15
//   layer odd  -> reads B (bf16x2, 4 B granule)  -> bank      = c & 31
__global__ __launch_bounds__(256) void balance_slots(ushort4* idx) {
  __shared__ unsigned char hist[256][4][32];  // 32 KB
  const int tid = blockIdx.x * blockDim.x + threadIdx.x;  // 0..511
  const int l = tid >> 6;        // layer 0..7
  const int g = tid & 63;        // group within layer
  const int w = g >> 4;          // wave 0..3
  const int i = g & 15;          // iteration 0..15
  unsigned char (*h)[32] = hist[threadIdx.x];
  for (int s = 0; s < 4; ++s)
    for (int b = 0; b < 32; ++b) h[s][b] = 0;
  const int mask = ((l & 1) == 0) ? 15 : 31;
  const int base = l * NODES + w * 64 + i * THREADS;
  for (int lane = 0; lane < 64; ++lane) {
    ushort4 c = idx[base + lane];
    unsigned short v[4] = {c.x, c.y, c.z, c.w};
    unsigned short o[4];
    bool used[4] = {false, false, false, false};
    for (int k = 0; k < 4; ++k) {
      const int b = v[k] & mask;
      int best = -1, bl = 256;
      for (int s = 0; s < 4; ++s)
        if (!used[s] && (int)h[s][b] < bl) { bl = h[s][b]; best = s; }
      used[best] = true; o[best] = v[k]; h[best][b]++;
    }
    idx[base + lane] = make_ushort4(o[0], o[1], o[2], o[3]);
  }
}

extern "C" void kernel_launch(void* const* d_in, const int* in_sizes, int n_in,
                              void* d_out, int out_size, void* d_ws, size_t ws_size,
                              hipStream_t stream) {
  const float* x          = (const float*)d_in[0];
  const unsigned char* mg = (const unsigned char*)d_in[1];
  const int* cidx         = (const int*)d_in[2];
  float* out              = (float*)d_out;

  const size_t need = (size_t)N_LAYERS * NODES * sizeof(ushort4);  // 256 KB
  if (ws_size >= need) {
    ushort4* packed = (ushort4*)d_ws;
    hipLaunchKernelGGL(pack_idx, dim3((N_LAYERS * NODES) / 256), dim3(256), 0, stream,
                       cidx, packed);
    hipLaunchKernelGGL(balance_slots, dim3(2), dim3(256), 0, stream, packed);
    hipLaunchKernelGGL(spn_packed, dim3(BATCH / RPB), dim3(THREADS), 0, stream,
                       x, mg, packed, out);
  } else {
    hipLaunchKernelGGL(spn_raw, dim3(BATCH / RPB), dim3(THREADS), 0, stream,
                       x, mg, cidx, out);
  }
}

// Round 5
// 222.891 us; speedup vs baseline: 1.2813x; 1.2813x over previous
//
#include <hip/hip_runtime.h>

constexpr int N_VARS   = 2048;
constexpr int NODES    = 4096;
constexpr int N_LAYERS = 8;
constexpr int BATCH    = 8192;
constexpr int THREADS  = 512;
constexpr int RPB      = 4;                 // batch rows per block (float4 / bf16x4)
constexpr int NPT      = NODES / THREADS;   // 8 nodes/thread/layer
constexpr size_t SMEM  = (size_t)NODES * 16 + (size_t)NODES * 8;  // A 64K + B 32K

// ---- bf16x2 word = rowA bf16 (low 16) | rowB bf16 (high 16) ----
__device__ __forceinline__ float bflo(unsigned w) { return __uint_as_float(w << 16); }
__device__ __forceinline__ float bfhi(unsigned w) { return __uint_as_float(w & 0xffff0000u); }
__device__ __forceinline__ unsigned bfpack(float a, float b) {   // RNE both
  unsigned ua = __float_as_uint(a), ub = __float_as_uint(b);
  ua = (ua + 0x7fffu + ((ua >> 16) & 1u)) >> 16;
  ub = (ub + 0x7fffu + ((ub >> 16) & 1u)) & 0xffff0000u;
  return ua | ub;
}

// MODE: 0 = pre-packed ushort4 (d_ws), 1 = raw int32, 2 = raw int64 words
template <int MODE>
__device__ __forceinline__ ushort4 get_idx(const void* p, int n) {
  if (MODE == 0) return ((const ushort4*)p)[n];
  if (MODE == 1) {
    int4 c = ((const int4*)p)[n];
    return make_ushort4((unsigned short)c.x, (unsigned short)c.y,
                        (unsigned short)c.z, (unsigned short)c.w);
  }
  const int* q = (const int*)p + (size_t)n * 8;
  return make_ushort4((unsigned short)q[0], (unsigned short)q[2],
                      (unsigned short)q[4], (unsigned short)q[6]);
}
template <int MODE> __device__ __forceinline__ size_t layer_bytes() {
  return MODE == 0 ? (size_t)NODES * 8 : MODE == 1 ? (size_t)NODES * 16
                                                   : (size_t)NODES * 32;
}

// Prod layer: gather fp32 float4 (4 rows) from A, multiply, store bf16x4 to B.
template <int MODE>
__device__ __forceinline__ void prod_pass(const float4* A, uint2* B,
                                          const void* idx, int t) {
#pragma unroll
  for (int i = 0; i < NPT; ++i) {
    const int n = t + i * THREADS;
    ushort4 c = get_idx<MODE>(idx, n);
    float4 a = A[c.x], b = A[c.y], d = A[c.z], e = A[c.w];
    B[n] = make_uint2(bfpack(a.x * b.x * d.x * e.x, a.y * b.y * d.y * e.y),
                      bfpack(a.z * b.z * d.z * e.z, a.w * b.w * d.w * e.w));
  }
}

// Sum layer: gather bf16x4 from B, add fp32, store float4 to A.
template <int MODE>
__device__ __forceinline__ void sum_pass(const uint2* B, float4* A,
                                         const void* idx, int t) {
#pragma unroll
  for (int i = 0; i < NPT; ++i) {
    const int n = t + i * THREADS;
    ushort4 c = get_idx<MODE>(idx, n);
    uint2 a = B[c.x], b = B[c.y], d = B[c.z], e = B[c.w];
    A[n] = make_float4(bflo(a.x) + bflo(b.x) + bflo(d.x) + bflo(e.x),
                       bfhi(a.x) + bfhi(b.x) + bfhi(d.x) + bfhi(e.x),
                       bflo(a.y) + bflo(b.y) + bflo(d.y) + bflo(e.y),
                       bfhi(a.y) + bfhi(b.y) + bfhi(d.y) + bfhi(e.y));
  }
}

template <int MODE>
__device__ __forceinline__ void spn_body(const float* __restrict__ x,
                                         const unsigned char* __restrict__ marg,
                                         const void* __restrict__ idx,
                                         float* __restrict__ out,
                                         float4* A, uint2* B) {
  const int t = threadIdx.x;
  const int row0 = blockIdx.x * RPB;
  const float* x0 = x + (size_t)row0 * N_VARS;
  const float* x1 = x0 + N_VARS;
  const float* x2 = x1 + N_VARS;
  const float* x3 = x2 + N_VARS;

#pragma unroll
  for (int i = 0; i < N_VARS / THREADS; ++i) {  // 4 iterations
    const int j = t + i * THREADS;
    float a0 = x0[j], a1 = x1[j], a2 = x2[j], a3 = x3[j];
    const bool m = marg[j] != 0;
    if (m) { a0 = a1 = a2 = a3 = 1.f; }
    A[j]          = make_float4(a0, a1, a2, a3);
    A[N_VARS + j] = m ? make_float4(1.f, 1.f, 1.f, 1.f)
                      : make_float4(1.f - a0, 1.f - a1, 1.f - a2, 1.f - a3);
  }

  const char* ib = (const char*)idx;
  const size_t LB = layer_bytes<MODE>();
  __syncthreads();
  prod_pass<MODE>(A, B, ib + 0 * LB, t); __syncthreads();   // L0
  sum_pass <MODE>(B, A, ib + 1 * LB, t); __syncthreads();   // L1
  prod_pass<MODE>(A, B, ib + 2 * LB, t); __syncthreads();   // L2
  sum_pass <MODE>(B, A, ib + 3 * LB, t); __syncthreads();   // L3
  prod_pass<MODE>(A, B, ib + 4 * LB, t); __syncthreads();   // L4
  sum_pass <MODE>(B, A, ib + 5 * LB, t); __syncthreads();   // L5
  prod_pass<MODE>(A, B, ib + 6 * LB, t); __syncthreads();   // L6

  // L7 (sum) fused into node reduction.
  float s0 = 0.f, s1 = 0.f, s2 = 0.f, s3 = 0.f;
  {
    const void* L7 = ib + 7 * LB;
#pragma unroll
    for (int i = 0; i < NPT; ++i) {
      const int n = t + i * THREADS;
      ushort4 c = get_idx<MODE>(L7, n);
      uint2 a = B[c.x], b = B[c.y], d = B[c.z], e = B[c.w];
      s0 += bflo(a.x) + bflo(b.x) + bflo(d.x) + bflo(e.x);
      s1 += bfhi(a.x) + bfhi(b.x) + bfhi(d.x) + bfhi(e.x);
      s2 += bflo(a.y) + bflo(b.y) + bflo(d.y) + bflo(e.y);
      s3 += bfhi(a.y) + bfhi(b.y) + bfhi(d.y) + bfhi(e.y);
    }
  }
#pragma unroll
  for (int off = 32; off > 0; off >>= 1) {
    s0 += __shfl_down(s0, off);
    s1 += __shfl_down(s1, off);
    s2 += __shfl_down(s2, off);
    s3 += __shfl_down(s3, off);
  }
  if ((t & 63) == 0) A[t >> 6] = make_float4(s0, s1, s2, s3);  // 8 wave partials
  __syncthreads();
  if (t == 0) {
    float4 tot = A[0];
#pragma unroll
    for (int w = 1; w < THREADS / 64; ++w) {
      float4 p = A[w];
      tot.x += p.x; tot.y += p.y; tot.z += p.z; tot.w += p.w;
    }
    ((float4*)out)[blockIdx.x] = tot;   // rows row0..row0+3
  }
}

extern __shared__ char smem[];

__global__ __launch_bounds__(THREADS) void spn_packed4(
    const float* __restrict__ x, const unsigned char* __restrict__ marg,
    const ushort4* __restrict__ idx, float* __restrict__ out) {
  float4* A = (float4*)smem;                    // 64 KB
  uint2*  B = (uint2*)(smem + NODES * 16);      // 32 KB
  spn_body<0>(x, marg, idx, out, A, B);
}

__global__ __launch_bounds__(THREADS) void spn_raw4(
    const float* __restrict__ x, const unsigned char* __restrict__ marg,
    const int* __restrict__ cidx, float* __restrict__ out) {
  float4* A = (float4*)smem;
  uint2*  B = (uint2*)(smem + NODES * 16);
  int acc = 0;  // int64 storage => odd words all zero (indices < 4096)
#pragma unroll
  for (int k = 0; k < 8; ++k) acc |= cidx[2 * k + 1];
  if (acc == 0) spn_body<2>(x, marg, cidx, out, A, B);
  else          spn_body<1>(x, marg, cidx, out, A, B);
}

// Fused pack + bank-balance. One thread per 64-node wave-instruction group
// (8 blocks = layers, 64 threads = groups). Prod/sum commute, so each node's
// 4 children are permuted across the 4 gather slots; greedy per group keeps
// each slot's per-bank multiplicity near hist/4.
//   even layers read A (16 B granule) -> bank-quad = c & 7
//   odd  layers read B ( 8 B granule) -> bank-pair = c & 15
// Histograms: 4 slot-counts packed per u32, row stride 17 (coprime w/ 32
// banks). Raw idx staged via coalesced loads into padded LDS.
__global__ __launch_bounds__(64) void prep_idx(const int* __restrict__ cidx,
                                               ushort4* __restrict__ out) {
  __shared__ ushort4  idxbuf[64][65];   // [group][lane], pad 65 vs bank aliasing
  __shared__ unsigned hist[64][17];     // [thread][bank] packed 4-slot counts
  const int l = blockIdx.x;             // layer
  const int t = threadIdx.x;            // group id; also lane for coop load

  int acc = 0;
#pragma unroll
  for (int k = 0; k < 8; ++k) acc |= cidx[2 * k + 1];
  const bool i64 = (acc == 0);

  const size_t lbase = (size_t)l * NODES;
  for (int g = 0; g < 64; ++g) {        // coalesced: lane t reads node g*64+t
    const size_t n = lbase + g * 64 + t;
    ushort4 r;
    if (i64) {
      const int4* p = (const int4*)cidx + n * 2;
      int4 u = p[0], v = p[1];
      r = make_ushort4((unsigned short)u.x, (unsigned short)u.z,
                       (unsigned short)v.x, (unsigned short)v.z);
    } else {
      int4 u = ((const int4*)cidx)[n];
      r = make_ushort4((unsigned short)u.x, (unsigned short)u.y,
                       (unsigned short)u.z, (unsigned short)u.w);
    }
    idxbuf[g][t] = r;
  }
#pragma unroll
  for (int b = 0; b < 17; ++b) hist[t][b] = 0;
  __syncthreads();

  const int mask = ((l & 1) == 0) ? 7 : 15;
  unsigned* h = hist[t];
  for (int lane = 0; lane < 64; ++lane) {
    ushort4 c = idxbuf[t][lane];
    unsigned short v[4] = {c.x, c.y, c.z, c.w};
    int bank[4]; unsigned wv[4];
#pragma unroll
    for (int k = 0; k < 4; ++k) bank[k] = v[k] & mask;
#pragma unroll
    for (int k = 0; k < 4; ++k) wv[k] = h[bank[k]];  // 4 independent ds_reads
    int slot[4]; unsigned used = 0;
    unsigned short o[4];
#pragma unroll
    for (int k = 0; k < 4; ++k) {
      unsigned eff = wv[k];
#pragma unroll
      for (int j = 0; j < 4; ++j)
        if (j < k && bank[j] == bank[k]) eff += 1u << (8 * slot[j]);
      const unsigned m2 = eff | used;   // used slots -> 0xff, never min
      int best = 0; unsigned bv = m2 & 0xffu;
#pragma unroll
      for (int s = 1; s < 4; ++s) {
        const unsigned q = (m2 >> (8 * s)) & 0xffu;
        if (q < bv) { bv = q; best = s; }
      }
      slot[k] = best; used |= 0xffu << (8 * best); o[best] = v[k];
    }
#pragma unroll
    for (int k = 0; k < 4; ++k) {       // write back (dups write same value)
      unsigned fin = wv[k];
#pragma unroll
      for (int j = 0; j < 4; ++j)
        if (bank[j] == bank[k]) fin += 1u << (8 * slot[j]);
      h[bank[k]] = fin;
    }
    out[lbase + t * 64 + lane] = make_ushort4(o[0], o[1], o[2], o[3]);
  }
}

extern "C" void kernel_launch(void* const* d_in, const int* in_sizes, int n_in,
                              void* d_out, int out_size, void* d_ws, size_t ws_size,
                              hipStream_t stream) {
  const float* x          = (const float*)d_in[0];
  const unsigned char* mg = (const unsigned char*)d_in[1];
  const int* cidx         = (const int*)d_in[2];
  float* out              = (float*)d_out;

  (void)hipFuncSetAttribute((const void*)spn_packed4,
                            hipFuncAttributeMaxDynamicSharedMemorySize, (int)SMEM);
  (void)hipFuncSetAttribute((const void*)spn_raw4,
                            hipFuncAttributeMaxDynamicSharedMemorySize, (int)SMEM);

  const size_t need = (size_t)N_LAYERS * NODES * sizeof(ushort4);  // 256 KB
  if (ws_size >= need) {
    ushort4* packed = (ushort4*)d_ws;
    hipLaunchKernelGGL(prep_idx, dim3(N_LAYERS), dim3(64), 0, stream, cidx, packed);
    hipLaunchKernelGGL(spn_packed4, dim3(BATCH / RPB), dim3(THREADS), SMEM, stream,
                       x, mg, packed, out);
  } else {
    hipLaunchKernelGGL(spn_raw4, dim3(BATCH / RPB), dim3(THREADS), SMEM, stream,
                       x, mg, cidx, out);
  }
}

// Round 6
// 212.710 us; speedup vs baseline: 1.3427x; 1.0479x over previous
//
#include <hip/hip_runtime.h>

constexpr int N_VARS   = 2048;
constexpr int NODES    = 4096;
constexpr int N_LAYERS = 8;
constexpr int BATCH    = 8192;
constexpr int THREADS  = 1024;              // 16 waves/block, 2 blocks/CU (48 KB LDS)
constexpr int RPB      = 2;                 // batch rows per block
constexpr int NPT      = NODES / THREADS;   // 4 nodes/thread/layer

// ---- bf16x2 word = row0 bf16 (low 16) | row1 bf16 (high 16) ----
__device__ __forceinline__ float bflo(unsigned w) { return __uint_as_float(w << 16); }
__device__ __forceinline__ float bfhi(unsigned w) { return __uint_as_float(w & 0xffff0000u); }
__device__ __forceinline__ unsigned bfpack(float a, float b) {   // RNE both
  unsigned ua = __float_as_uint(a), ub = __float_as_uint(b);
  ua = (ua + 0x7fffu + ((ua >> 16) & 1u)) >> 16;
  ub = (ub + 0x7fffu + ((ub >> 16) & 1u)) & 0xffff0000u;
  return ua | ub;
}

// MODE: 0 = pre-packed ushort4 (d_ws), 1 = raw int32, 2 = raw int64 words
template <int MODE>
__device__ __forceinline__ ushort4 get_idx(const void* p, int n) {
  if (MODE == 0) return ((const ushort4*)p)[n];
  if (MODE == 1) {
    int4 c = ((const int4*)p)[n];
    return make_ushort4((unsigned short)c.x, (unsigned short)c.y,
                        (unsigned short)c.z, (unsigned short)c.w);
  }
  const int* q = (const int*)p + (size_t)n * 8;
  return make_ushort4((unsigned short)q[0], (unsigned short)q[2],
                      (unsigned short)q[4], (unsigned short)q[6]);
}
template <int MODE> __device__ __forceinline__ size_t layer_bytes() {
  return MODE == 0 ? (size_t)NODES * 8 : MODE == 1 ? (size_t)NODES * 16
                                                   : (size_t)NODES * 32;
}

// Prod layer: gather fp32 float2 from A, multiply fp32, store bf16x2 to B.
template <int MODE>
__device__ __forceinline__ void prod_pass(const float2* A, unsigned* B,
                                          const void* idx, int t) {
#pragma unroll
  for (int i = 0; i < NPT; ++i) {
    const int n = t + i * THREADS;
    ushort4 c = get_idx<MODE>(idx, n);
    float2 a = A[c.x], b = A[c.y], d = A[c.z], e = A[c.w];
    B[n] = bfpack(a.x * b.x * d.x * e.x, a.y * b.y * d.y * e.y);
  }
}

// Sum layer: gather bf16x2 from B, add fp32, store fp32 float2 to A.
template <int MODE>
__device__ __forceinline__ void sum_pass(const unsigned* B, float2* A,
                                         const void* idx, int t) {
#pragma unroll
  for (int i = 0; i < NPT; ++i) {
    const int n = t + i * THREADS;
    ushort4 c = get_idx<MODE>(idx, n);
    unsigned a = B[c.x], b = B[c.y], d = B[c.z], e = B[c.w];
    A[n] = make_float2(bflo(a) + bflo(b) + bflo(d) + bflo(e),
                       bfhi(a) + bfhi(b) + bfhi(d) + bfhi(e));
  }
}

template <int MODE>
__device__ __forceinline__ void spn_body(const float* __restrict__ x,
                                         const unsigned char* __restrict__ marg,
                                         const void* __restrict__ idx,
                                         float* __restrict__ out,
                                         float2* A,          // 4096 fp32x2 = 32 KB
                                         unsigned* B) {      // 4096 bf16x2 = 16 KB
  const int t = threadIdx.x;
  const int row0 = blockIdx.x * RPB;
  const float* x0 = x + (size_t)row0 * N_VARS;
  const float* x1 = x0 + N_VARS;

#pragma unroll
  for (int i = 0; i < N_VARS / THREADS; ++i) {  // 2 iterations
    const int j = t + i * THREADS;
    const float a = x0[j], b = x1[j];
    const bool m = marg[j] != 0;
    A[j]          = make_float2(m ? 1.f : a,       m ? 1.f : b);
    A[N_VARS + j] = make_float2(m ? 1.f : 1.f - a, m ? 1.f : 1.f - b);
  }

  const char* ib = (const char*)idx;
  const size_t LB = layer_bytes<MODE>();
  __syncthreads();
  prod_pass<MODE>(A, B, ib + 0 * LB, t); __syncthreads();   // L0
  sum_pass <MODE>(B, A, ib + 1 * LB, t); __syncthreads();   // L1
  prod_pass<MODE>(A, B, ib + 2 * LB, t); __syncthreads();   // L2
  sum_pass <MODE>(B, A, ib + 3 * LB, t); __syncthreads();   // L3
  prod_pass<MODE>(A, B, ib + 4 * LB, t); __syncthreads();   // L4
  sum_pass <MODE>(B, A, ib + 5 * LB, t); __syncthreads();   // L5
  prod_pass<MODE>(A, B, ib + 6 * LB, t); __syncthreads();   // L6

  // L7 (sum) fused into node reduction.
  float s0 = 0.f, s1 = 0.f;
  {
    const void* L7 = ib + 7 * LB;
#pragma unroll
    for (int i = 0; i < NPT; ++i) {
      const int n = t + i * THREADS;
      ushort4 c = get_idx<MODE>(L7, n);
      unsigned a = B[c.x], b = B[c.y], d = B[c.z], e = B[c.w];
      s0 += bflo(a) + bflo(b) + bflo(d) + bflo(e);
      s1 += bfhi(a) + bfhi(b) + bfhi(d) + bfhi(e);
    }
  }
#pragma unroll
  for (int off = 32; off > 0; off >>= 1) {
    s0 += __shfl_down(s0, off);
    s1 += __shfl_down(s1, off);
  }
  if ((t & 63) == 0) A[t >> 6] = make_float2(s0, s1);  // 16 wave partials
  __syncthreads();
  if (t == 0) {
    float2 tot = A[0];
#pragma unroll
    for (int w = 1; w < THREADS / 64; ++w) { tot.x += A[w].x; tot.y += A[w].y; }
    ((float2*)out)[blockIdx.x] = tot;
  }
}

__global__ __launch_bounds__(THREADS, 8) void spn_packed(
    const float* __restrict__ x, const unsigned char* __restrict__ marg,
    const ushort4* __restrict__ idx, float* __restrict__ out) {
  __shared__ float2   A[NODES];   // 32 KB
  __shared__ unsigned B[NODES];   // 16 KB -> 48 KB total, 2 blocks/CU (wave-cap)
  spn_body<0>(x, marg, idx, out, A, B);
}

__global__ __launch_bounds__(THREADS, 8) void spn_raw(
    const float* __restrict__ x, const unsigned char* __restrict__ marg,
    const int* __restrict__ cidx, float* __restrict__ out) {
  __shared__ float2   A[NODES];
  __shared__ unsigned B[NODES];
  int acc = 0;  // int64 storage => odd words all zero (indices < 4096)
#pragma unroll
  for (int k = 0; k < 8; ++k) acc |= cidx[2 * k + 1];
  if (acc == 0) spn_body<2>(x, marg, cidx, out, A, B);
  else          spn_body<1>(x, marg, cidx, out, A, B);
}

// Fused pack + bank-balance, one WAVE per 64-node instruction-group.
// Prod/sum commute -> permute each node's 4 children across the 4 gather
// slots so each slot's per-bank multiplicity stays near hist/4.
//   even layers read A (float2, 8 B granule)  -> bank-pair = c & 15
//   odd  layers read B (bf16x2, 4 B granule)  -> bank      = c & 31
// Histogram lives distributed in registers: lane b holds bank b's four
// 8-bit slot counts packed in one u32. All lanes compute every decision
// redundantly from __shfl'd data (pure function -> identical results).
__global__ __launch_bounds__(64) void prep_idx(const int* __restrict__ cidx,
                                               ushort4* __restrict__ out) {
  const int gid  = blockIdx.x;        // 0..511
  const int l    = gid >> 6;          // layer
  const int cgrp = gid & 63;          // 64-node chunk within layer
  const int lane = threadIdx.x;       // 0..63
  const size_t n = (size_t)l * NODES + cgrp * 64 + lane;

  int acc = 0;                        // i64 storage detect (uniform)
#pragma unroll
  for (int k = 0; k < 8; ++k) acc |= cidx[2 * k + 1];

  ushort4 r;
  if (acc == 0) {
    const int4* p = (const int4*)cidx + n * 2;
    int4 u = p[0], v = p[1];
    r = make_ushort4((unsigned short)u.x, (unsigned short)u.z,
                     (unsigned short)v.x, (unsigned short)v.z);
  } else {
    int4 u = ((const int4*)cidx)[n];
    r = make_ushort4((unsigned short)u.x, (unsigned short)u.y,
                     (unsigned short)u.z, (unsigned short)u.w);
  }
  const unsigned w0 = (unsigned)r.x | ((unsigned)r.y << 16);
  const unsigned w1 = (unsigned)r.z | ((unsigned)r.w << 16);
  const int mask = ((l & 1) == 0) ? 15 : 31;

  unsigned hcnt = 0;                  // this lane's bank: 4 packed slot counts
  ushort4 mine = r;
  for (int k = 0; k < 64; ++k) {
    const unsigned a0 = __shfl(w0, k);
    const unsigned a1 = __shfl(w1, k);
    unsigned short v4[4] = {(unsigned short)(a0 & 0xffffu), (unsigned short)(a0 >> 16),
                            (unsigned short)(a1 & 0xffffu), (unsigned short)(a1 >> 16)};
    int bank[4];
#pragma unroll
    for (int j = 0; j < 4; ++j) bank[j] = v4[j] & mask;
    unsigned cnt[4];
#pragma unroll
    for (int j = 0; j < 4; ++j) cnt[j] = __shfl(hcnt, bank[j]);
    int slot[4]; unsigned used = 0;
    unsigned short o[4];
#pragma unroll
    for (int j = 0; j < 4; ++j) {
      unsigned eff = cnt[j];
#pragma unroll
      for (int p2 = 0; p2 < 4; ++p2)      // account earlier dup-bank children
        if (p2 < j && bank[p2] == bank[j]) eff += 1u << (8 * slot[p2]);
      const unsigned m2 = eff | used;     // used slots -> 0xff, never min
      int best = 0; unsigned bv = m2 & 0xffu;
#pragma unroll
      for (int s = 1; s < 4; ++s) {
        const unsigned q = (m2 >> (8 * s)) & 0xffu;
        if (q < bv) { bv = q; best = s; }
      }
      slot[j] = best; used |= 0xffu << (8 * best); o[best] = v4[j];
    }
#pragma unroll
    for (int j = 0; j < 4; ++j)           // owning lane updates its bank
      if (lane == bank[j]) hcnt += 1u << (8 * slot[j]);
    if (lane == k) mine = make_ushort4(o[0], o[1], o[2], o[3]);
  }
  out[n] = mine;   // coalesced ushort4 store
}

extern "C" void kernel_launch(void* const* d_in, const int* in_sizes, int n_in,
                              void* d_out, int out_size, void* d_ws, size_t ws_size,
                              hipStream_t stream) {
  const float* x          = (const float*)d_in[0];
  const unsigned char* mg = (const unsigned char*)d_in[1];
  const int* cidx         = (const int*)d_in[2];
  float* out              = (float*)d_out;

  const size_t need = (size_t)N_LAYERS * NODES * sizeof(ushort4);  // 256 KB
  if (ws_size >= need) {
    ushort4* packed = (ushort4*)d_ws;
    hipLaunchKernelGGL(prep_idx, dim3(N_LAYERS * 64), dim3(64), 0, stream,
                       cidx, packed);
    hipLaunchKernelGGL(spn_packed, dim3(BATCH / RPB), dim3(THREADS), 0, stream,
                       x, mg, packed, out);
  } else {
    hipLaunchKernelGGL(spn_raw, dim3(BATCH / RPB), dim3(THREADS), 0, stream,
                       x, mg, cidx, out);
  }
}